// Round 12
// baseline (1441.236 us; speedup 1.0000x reference)
//
#include <hip/hip_runtime.h>
#include <hip/hip_bf16.h>
#include <math.h>

#define N_ATOMS 20000
#define N_EDGES 320000
#define FEAT 128
#define N_RBF 20
#define N_CONV 3
#define N_OUT_ 5
#define PI_F 3.14159265358979f
#define M20P 20032
#define M60PAD 60160   // v-pair rows padded past 60102 (dual_vn 126-row overlap reads)

typedef unsigned short ushort;
typedef __bf16 bf16x8 __attribute__((ext_vector_type(8)));
typedef float f32x4 __attribute__((ext_vector_type(4)));

__device__ __forceinline__ float b2f(ushort u){ return __uint_as_float(((unsigned)u) << 16); }
__device__ __forceinline__ ushort f2b(float x){
    unsigned u = __float_as_uint(x);
    return (ushort)((u + 0x7FFFu + ((u >> 16) & 1u)) >> 16);   // RNE
}
#define MFMA __builtin_amdgcn_mfma_f32_16x16x32_bf16

// ---------------- workspace layout (float slots) ----------------
constexpr size_t rnd64(size_t x){ return (x + 63) & ~size_t(63); }
constexpr size_t F_XYZ  = 64;                                  // flag at ws[0]
constexpr size_t F_EMB  = rnd64(F_XYZ + 60000);
constexpr size_t F_B1   = rnd64(F_EMB + 12800);
constexpr size_t F_B2   = rnd64(F_B1  + 3*128);
constexpr size_t F_WD   = rnd64(F_B2  + 3*384);
constexpr size_t F_BD   = rnd64(F_WD  + 3*20*384);
constexpr size_t F_BS1  = rnd64(F_BD  + 3*384);
constexpr size_t F_BS2  = rnd64(F_BS1 + 3*128);
constexpr size_t F_BR1  = rnd64(F_BS2 + 3*384);
constexpr size_t F_BR2  = rnd64(F_BR1 + 128);
constexpr size_t F_BF1  = rnd64(F_BR2 + 64);
constexpr size_t F_BF2  = rnd64(F_BF1 + 128);
constexpr size_t F_BF3  = rnd64(F_BF2 + 128);
constexpr size_t F_CNT  = rnd64(F_BF3 + 8);                    // int
constexpr size_t F_ROW  = rnd64(F_CNT  + N_ATOMS);             // int, +1
constexpr size_t F_CUR  = rnd64(F_ROW  + N_ATOMS + 1);         // int
constexpr size_t F_EID  = rnd64(F_CUR  + N_ATOMS);             // int
constexpr size_t F_EJ   = rnd64(F_EID  + N_EDGES);             // int, CSR-ordered j
constexpr size_t F_EREC = rnd64(F_EJ   + N_EDGES);             // 24 floats/edge, CSR order
constexpr size_t F_S    = rnd64(F_EREC + (size_t)N_EDGES*24);
constexpr size_t F_V    = rnd64(F_S    + (size_t)N_ATOMS*FEAT);
constexpr size_t F_PHI  = rnd64(F_V    + (size_t)60000*FEAT);     // phi f32, later uv f32
constexpr size_t F_VV   = rnd64(F_PHI  + (size_t)N_ATOMS*384);
constexpr size_t F_SPL  = rnd64(F_VV   + (size_t)60000*FEAT);     // CAT hi/lo lives here
constexpr size_t F_OUT  = rnd64(F_SPL  + (size_t)N_ATOMS*384);
// bf16 hi/lo pair buffers (slot counts = elems/2)
constexpr size_t H_SHI  = rnd64(F_OUT  + N_ATOMS*N_OUT_);
constexpr size_t H_SLO  = rnd64(H_SHI  + (size_t)M20P*128/2);
constexpr size_t H_VHI  = rnd64(H_SLO  + (size_t)M20P*128/2);
constexpr size_t H_VLO  = rnd64(H_VHI  + (size_t)M60PAD*128/2);
constexpr size_t H_HAHI = rnd64(H_VLO  + (size_t)M60PAD*128/2);
constexpr size_t H_HALO = rnd64(H_HAHI + (size_t)M20P*128/2);
constexpr size_t H_HBHI = rnd64(H_HALO + (size_t)M20P*128/2);
constexpr size_t H_HBLO = rnd64(H_HBHI + (size_t)M20P*128/2);
constexpr size_t H_AFHI = rnd64(H_HBLO + (size_t)M20P*128/2);
constexpr size_t H_AFLO = rnd64(H_AFHI + (size_t)M20P*64/2);
constexpr size_t H_WT   = rnd64(H_AFLO + (size_t)M20P*64/2);
// weight offsets (ushort elems within hi half; lo = +O_WTOT)
constexpr size_t O_W1T=0, O_W2T=49152, O_UT=196608, O_VT=245760, O_WS1T=294912,
                 O_WS2T=393216, O_WR1T=540672, O_WR2T=557056, O_WF1T=565248,
                 O_WF2T=573440, O_WF3T=589824, O_WTOT=598016;

// ---------------- dtype detection ----------------
__global__ void k_detect(const unsigned int* __restrict__ bits, int* flag){
    __shared__ int cnt;
    if (threadIdx.x == 0) cnt = 0;
    __syncthreads();
    unsigned int lo = bits[threadIdx.x] & 0xFFFFu;
    if (lo >= 0x3000u && lo <= 0x4100u) atomicAdd(&cnt, 1);
    __syncthreads();
    if (threadIdx.x == 0) *flag = (cnt >= 48) ? 1 : 0;
}

// ---------------- mega f32-convert (13 segments, 1 launch) ----------------
struct P13 { const void* p[13]; };
__global__ void k_cvt_all(P13 sp, float* __restrict__ ws, const int* __restrict__ flag){
    constexpr int   NSEG = 13;
    constexpr int    SZ[NSEG] = {60000,12800,384,1152,23040,1152,384,1152,128,64,128,128,5};
    constexpr size_t DO_[NSEG]= {F_XYZ,F_EMB,F_B1,F_B2,F_WD,F_BD,F_BS1,F_BS2,F_BR1,F_BR2,F_BF1,F_BF2,F_BF3};
    int t = blockIdx.x * blockDim.x + threadIdx.x;
    int bf = *flag;
    #pragma unroll
    for (int s = 0; s < NSEG; s++){
        if (t < SZ[s]){
            float v = bf ? b2f(((const ushort*)sp.p[s])[t]) : ((const float*)sp.p[s])[t];
            ws[DO_[s] + t] = v;
            return;
        }
        t -= SZ[s];
    }
}

// ---------------- mega weight transpose hi/lo (23 segments, 1 launch) -------
// PM=1 segments (Ws2): output-channel rows permuted gate-major:
// n -> (g/64)*192 + gate*64 + (g%64), g=n&127, gate=n>>7  (for k_ws2up)
struct P11 { const void* p[11]; };
__global__ void k_wt_all(P11 sp, ushort* __restrict__ wb, const int* __restrict__ flag){
    constexpr int NSEG = 23;
    constexpr int SRC[NSEG]  = {0,1,2,3,4,5, 0,1,2,3,4,5, 0,1,2,3,4,5, 6,7,8,9,10};
    constexpr int SOFF[NSEG] = {0,0,0,0,0,0, 16384,49152,16384,16384,32768,49152,
                                32768,98304,32768,32768,65536,98304, 0,0,0,0,0};
    constexpr size_t DOFF[NSEG]={O_W1T,O_W2T,O_UT,O_VT,O_WS1T,O_WS2T,
                                 O_W1T+16384,O_W2T+49152,O_UT+16384,O_VT+16384,O_WS1T+32768,O_WS2T+49152,
                                 O_W1T+32768,O_W2T+98304,O_UT+32768,O_VT+32768,O_WS1T+65536,O_WS2T+98304,
                                 O_WR1T,O_WR2T,O_WF1T,O_WF2T,O_WF3T};
    constexpr int KK[NSEG]   = {128,128,128,128,256,128, 128,128,128,128,256,128,
                                128,128,128,128,256,128, 128,128,64,128,128};
    constexpr int NN[NSEG]   = {128,384,128,128,128,384, 128,384,128,128,128,384,
                                128,384,128,128,128,384, 128,64,128,128,5};
    constexpr int NP[NSEG]   = {128,384,128,128,128,384, 128,384,128,128,128,384,
                                128,384,128,128,128,384, 128,64,128,128,64};
    constexpr int PM[NSEG]   = {0,0,0,0,0,1, 0,0,0,0,0,1, 0,0,0,0,0,1, 0,0,0,0,0};
    int t = blockIdx.x * blockDim.x + threadIdx.x;
    int bf = *flag;
    #pragma unroll
    for (int s = 0; s < NSEG; s++){
        int tot = NP[s] * KK[s];
        if (t < tot){
            int n = t / KK[s], k = t & (KK[s] - 1);
            ushort hi = 0, lo = 0;
            if (n < NN[s]){
                int si = SOFF[s] + k * NN[s] + n;
                float w = bf ? b2f(((const ushort*)sp.p[SRC[s]])[si])
                             : ((const float*)sp.p[SRC[s]])[si];
                hi = f2b(w); lo = f2b(w - b2f(hi));
            }
            int dr = n;
            if (PM[s]) { int g = n & 127, tg = n >> 7; dr = (g >> 6) * 192 + tg * 64 + (g & 63); }
            size_t di = DOFF[s] + (size_t)dr * KK[s] + k;
            wb[di] = hi;
            wb[O_WTOT + di] = lo;
            return;
        }
        t -= tot;
    }
}
constexpr int WT_TOTAL = 598016;

__global__ void k_store_out(const float* __restrict__ src, void* __restrict__ dst, int n,
                            const int* __restrict__ flag){
    int t = blockIdx.x * blockDim.x + threadIdx.x;
    if (t >= n) return;
    float v = src[t];
    if (*flag) ((ushort*)dst)[t] = f2b(v);
    else       ((float*)dst)[t] = v;
}

// ---------------- utility ----------------
__global__ void k_zero_i(int* p, int n){
    int t = blockIdx.x * blockDim.x + threadIdx.x;
    if (t < n) p[t] = 0;
}
__global__ void k_init_s(const float* __restrict__ embed, const int* __restrict__ z,
                         float* __restrict__ s, ushort* __restrict__ shi,
                         ushort* __restrict__ slo){
    int t = blockIdx.x * blockDim.x + threadIdx.x;
    if (t >= N_ATOMS * FEAT) return;
    int n = t >> 7, f = t & 127;
    float v = embed[z[n] * FEAT + f];
    s[t] = v;
    ushort h = f2b(v); shi[t] = h; slo[t] = f2b(v - b2f(h));
}

// ---------------- CSR build ----------------
__global__ void k_hist(const int* __restrict__ nbrs, int* __restrict__ cnt){
    int e = blockIdx.x * blockDim.x + threadIdx.x;
    if (e < N_EDGES) atomicAdd(&cnt[nbrs[2*e]], 1);
}
__global__ void k_scan(const int* __restrict__ cnt, int* __restrict__ row, int* __restrict__ cur){
    __shared__ int ls[256];
    int t = threadIdx.x, base = t * 80;
    int s = 0;
    for (int k = 0; k < 80; k++){ int i = base + k; if (i < N_ATOMS) s += cnt[i]; }
    ls[t] = s; __syncthreads();
    for (int off = 1; off < 256; off <<= 1){
        int v = (t >= off) ? ls[t - off] : 0;
        __syncthreads();
        ls[t] += v;
        __syncthreads();
    }
    int run = ls[t] - s;
    for (int k = 0; k < 80; k++){
        int i = base + k;
        if (i < N_ATOMS){ row[i] = run; cur[i] = run; run += cnt[i]; }
    }
    if (t == 255) row[N_ATOMS] = ls[255];
}
__global__ void k_fill(const int* __restrict__ nbrs, int* __restrict__ cur, int* __restrict__ eid){
    int e = blockIdx.x * blockDim.x + threadIdx.x;
    if (e >= N_EDGES) return;
    int p = atomicAdd(&cur[nbrs[2*e]], 1);
    eid[p] = e;
}

// ---------------- geometry in CSR order: EJ + packed 24-float record --------
__global__ void k_geom_csr(const float* __restrict__ xyz, const int* __restrict__ nbrs,
                           const int* __restrict__ eid,
                           int* __restrict__ EJ, float* __restrict__ EREC){
    int idx = blockIdx.x * blockDim.x + threadIdx.x;
    if (idx >= N_EDGES) return;
    int e = eid[idx];
    int i = nbrs[2*e], j = nbrs[2*e+1];
    float rx = xyz[3*j]   - xyz[3*i];
    float ry = xyz[3*j+1] - xyz[3*i+1];
    float rz = xyz[3*j+2] - xyz[3*i+2];
    float d  = sqrtf(rx*rx + ry*ry + rz*rz + 1e-12f);
    float inv = 1.0f / d;
    float b  = PI_F * d * 0.2f;
    float sb = sinf(b), cb = cosf(b);
    float fc = (d < 5.0f) ? 0.5f * (cb + 1.0f) : 0.0f;
    float scale = inv * fc, c2 = 2.0f * cb;
    EJ[idx] = j;
    float* rec = EREC + (size_t)idx * 24;
    rec[0] = fc; rec[1] = rx*inv; rec[2] = ry*inv; rec[3] = rz*inv;
    float sp = 0.f, sc = sb;
    #pragma unroll
    for (int r = 0; r < N_RBF; r++){
        rec[4 + r] = sc * scale;
        float sn = c2 * sc - sp;
        sp = sc; sc = sn;
    }
}

// ---------------- split-bf16 MFMA GEMM, fat wave tile 32x64 ----------------
template<int KT>
__global__ __launch_bounds__(256) void k_gemm3t(
    const ushort* __restrict__ Ahi, const ushort* __restrict__ Alo,
    const ushort* __restrict__ Bthi, const ushort* __restrict__ Btlo,
    const float* __restrict__ bias, int M, int N, int act,
    float* __restrict__ Cf, ushort* __restrict__ Chi, ushort* __restrict__ Clo)
{
    int wave = threadIdx.x >> 6, lane = threadIdx.x & 63;
    int l15 = lane & 15, quad = lane >> 4;
    int m0 = blockIdx.y * 128 + wave * 32;
    int n0 = blockIdx.x * 64;
    const ushort* aph = Ahi  + (size_t)(m0 + l15) * KT + quad * 8;
    const ushort* apl = Alo  + (size_t)(m0 + l15) * KT + quad * 8;
    const ushort* bph = Bthi + (size_t)(n0 + l15) * KT + quad * 8;
    const ushort* bpl = Btlo + (size_t)(n0 + l15) * KT + quad * 8;
    f32x4 acc[2][4];
    #pragma unroll
    for (int r = 0; r < 2; r++)
        #pragma unroll
        for (int c = 0; c < 4; c++) acc[r][c] = (f32x4){0.f, 0.f, 0.f, 0.f};
    #pragma unroll
    for (int k0 = 0; k0 < KT; k0 += 32) {
        bf16x8 ah0 = *reinterpret_cast<const bf16x8*>(aph + k0);
        bf16x8 al0 = *reinterpret_cast<const bf16x8*>(apl + k0);
        bf16x8 ah1 = *reinterpret_cast<const bf16x8*>(aph + (size_t)16 * KT + k0);
        bf16x8 al1 = *reinterpret_cast<const bf16x8*>(apl + (size_t)16 * KT + k0);
        #pragma unroll
        for (int c = 0; c < 4; c++) {
            bf16x8 bh = *reinterpret_cast<const bf16x8*>(bph + (size_t)c * 16 * KT + k0);
            bf16x8 bl = *reinterpret_cast<const bf16x8*>(bpl + (size_t)c * 16 * KT + k0);
            acc[0][c] = MFMA(al0, bh, acc[0][c], 0, 0, 0);
            acc[0][c] = MFMA(ah0, bl, acc[0][c], 0, 0, 0);
            acc[0][c] = MFMA(ah0, bh, acc[0][c], 0, 0, 0);
            acc[1][c] = MFMA(al1, bh, acc[1][c], 0, 0, 0);
            acc[1][c] = MFMA(ah1, bl, acc[1][c], 0, 0, 0);
            acc[1][c] = MFMA(ah1, bh, acc[1][c], 0, 0, 0);
        }
    }
    #pragma unroll
    for (int rr = 0; rr < 2; rr++) {
        int row_base = m0 + rr * 16 + quad * 4;
        #pragma unroll
        for (int c = 0; c < 4; c++) {
            int col = n0 + c * 16 + l15;
            #pragma unroll
            for (int r = 0; r < 4; r++) {
                int row = row_base + r;
                if (row < M && col < N) {
                    float v = acc[rr][c][r];
                    if (bias) v += bias[col];
                    if (act)  v = v / (1.f + expf(-v));
                    size_t idx = (size_t)row * N + col;
                    if (Cf)  Cf[idx] = v;
                    if (Chi) { ushort h = f2b(v); Chi[idx] = h; Clo[idx] = f2b(v - b2f(h)); }
                }
            }
        }
    }
}

// ---------------- dual GEMM (uv,vv) + fused vnorm/cat, atom-aligned 126-row --
__global__ __launch_bounds__(256) void k_dual_vn(
    const ushort* __restrict__ Ahi, const ushort* __restrict__ Alo,
    const ushort* __restrict__ B1hi, const ushort* __restrict__ B1lo,
    const ushort* __restrict__ B2hi, const ushort* __restrict__ B2lo,
    const float* __restrict__ s,
    float* __restrict__ C1, float* __restrict__ C2,
    ushort* __restrict__ chi, ushort* __restrict__ clo)
{
    constexpr int KT = 128, N = 128, MROWS = 60000, LDV = 68;
    __shared__ float vvs[128 * LDV];   // 34.8 KB
    int wave = threadIdx.x >> 6, lane = threadIdx.x & 63;
    int l15 = lane & 15, quad = lane >> 4;
    int m0 = blockIdx.y * 126 + wave * 32;
    int n0 = blockIdx.x * 64;
    const ushort* aph = Ahi  + (size_t)(m0 + l15) * KT + quad * 8;
    const ushort* apl = Alo  + (size_t)(m0 + l15) * KT + quad * 8;
    const ushort* b1h = B1hi + (size_t)(n0 + l15) * KT + quad * 8;
    const ushort* b1l = B1lo + (size_t)(n0 + l15) * KT + quad * 8;
    const ushort* b2h = B2hi + (size_t)(n0 + l15) * KT + quad * 8;
    const ushort* b2l = B2lo + (size_t)(n0 + l15) * KT + quad * 8;
    f32x4 acc1[2][4], acc2[2][4];
    #pragma unroll
    for (int r = 0; r < 2; r++)
        #pragma unroll
        for (int c = 0; c < 4; c++) {
            acc1[r][c] = (f32x4){0.f,0.f,0.f,0.f};
            acc2[r][c] = (f32x4){0.f,0.f,0.f,0.f};
        }
    #pragma unroll
    for (int k0 = 0; k0 < KT; k0 += 32) {
        bf16x8 ah0 = *reinterpret_cast<const bf16x8*>(aph + k0);
        bf16x8 al0 = *reinterpret_cast<const bf16x8*>(apl + k0);
        bf16x8 ah1 = *reinterpret_cast<const bf16x8*>(aph + (size_t)16 * KT + k0);
        bf16x8 al1 = *reinterpret_cast<const bf16x8*>(apl + (size_t)16 * KT + k0);
        #pragma unroll
        for (int c = 0; c < 4; c++) {
            bf16x8 bh = *reinterpret_cast<const bf16x8*>(b1h + (size_t)c * 16 * KT + k0);
            bf16x8 bl = *reinterpret_cast<const bf16x8*>(b1l + (size_t)c * 16 * KT + k0);
            acc1[0][c] = MFMA(al0, bh, acc1[0][c], 0, 0, 0);
            acc1[0][c] = MFMA(ah0, bl, acc1[0][c], 0, 0, 0);
            acc1[0][c] = MFMA(ah0, bh, acc1[0][c], 0, 0, 0);
            acc1[1][c] = MFMA(al1, bh, acc1[1][c], 0, 0, 0);
            acc1[1][c] = MFMA(ah1, bl, acc1[1][c], 0, 0, 0);
            acc1[1][c] = MFMA(ah1, bh, acc1[1][c], 0, 0, 0);
        }
        #pragma unroll
        for (int c = 0; c < 4; c++) {
            bf16x8 bh = *reinterpret_cast<const bf16x8*>(b2h + (size_t)c * 16 * KT + k0);
            bf16x8 bl = *reinterpret_cast<const bf16x8*>(b2l + (size_t)c * 16 * KT + k0);
            acc2[0][c] = MFMA(al0, bh, acc2[0][c], 0, 0, 0);
            acc2[0][c] = MFMA(ah0, bl, acc2[0][c], 0, 0, 0);
            acc2[0][c] = MFMA(ah0, bh, acc2[0][c], 0, 0, 0);
            acc2[1][c] = MFMA(al1, bh, acc2[1][c], 0, 0, 0);
            acc2[1][c] = MFMA(ah1, bl, acc2[1][c], 0, 0, 0);
            acc2[1][c] = MFMA(ah1, bh, acc2[1][c], 0, 0, 0);
        }
    }
    #pragma unroll
    for (int rr = 0; rr < 2; rr++) {
        #pragma unroll
        for (int c = 0; c < 4; c++) {
            int col = n0 + c * 16 + l15;
            #pragma unroll
            for (int r = 0; r < 4; r++) {
                int lrow = wave * 32 + rr * 16 + quad * 4 + r;
                int row  = m0 + rr * 16 + quad * 4 + r;
                float vv = acc2[rr][c][r];
                vvs[lrow * LDV + c * 16 + l15] = vv;
                if (row < MROWS) {
                    size_t idx = (size_t)row * N + col;
                    C1[idx] = acc1[rr][c][r];
                    C2[idx] = vv;
                }
            }
        }
    }
    __syncthreads();
    // vnorm + cat for 42 atoms x 64 cols (LDS rows a_loc*3+d)
    int a0 = blockIdx.y * 42;
    for (int t = threadIdx.x; t < 42 * 64; t += 256) {
        int a_loc = t >> 6, c = t & 63;
        int a = a0 + a_loc;
        if (a >= N_ATOMS) continue;
        float v0 = vvs[(a_loc * 3 + 0) * LDV + c];
        float v1 = vvs[(a_loc * 3 + 1) * LDV + c];
        float v2 = vvs[(a_loc * 3 + 2) * LDV + c];
        float nr = sqrtf(v0 * v0 + v1 * v1 + v2 * v2 + 1e-12f);
        int g = n0 + c;
        float sv = s[(size_t)a * FEAT + g];
        size_t c0 = (size_t)a * 256 + g;
        ushort h;
        h = f2b(sv); chi[c0]       = h; clo[c0]       = f2b(sv - b2f(h));
        h = f2b(nr); chi[c0 + 128] = h; clo[c0 + 128] = f2b(nr - b2f(h));
    }
}

// ---------------- Ws2 GEMM (permuted cols) + fused gated update -------------
__global__ __launch_bounds__(384) void k_ws2up(
    const ushort* __restrict__ Ahi, const ushort* __restrict__ Alo,
    const ushort* __restrict__ Bphi, const ushort* __restrict__ Bplo,
    const float* __restrict__ bs2,
    const float* __restrict__ uv, const float* __restrict__ vvf,
    const ushort* __restrict__ vhi, const ushort* __restrict__ vlo,
    float* __restrict__ s, float* __restrict__ v,
    ushort* __restrict__ shi, ushort* __restrict__ slo, int M)
{
    constexpr int KT = 128, LDG = 200;          // 192 cols + 8 pad
    __shared__ float gl[64 * LDG];               // 50 KB -> 3 blocks/CU
    int wave = threadIdx.x >> 6, lane = threadIdx.x & 63;
    int l15 = lane & 15, quad = lane >> 4;
    int tg = wave >> 1, rh = wave & 1;           // gate, row-half
    int m0 = blockIdx.y * 64 + rh * 32;
    int X  = blockIdx.x;                         // g-half
    const ushort* aph = Ahi  + (size_t)(m0 + l15) * KT + quad * 8;
    const ushort* apl = Alo  + (size_t)(m0 + l15) * KT + quad * 8;
    const ushort* bph = Bphi + (size_t)(X * 192 + tg * 64 + l15) * KT + quad * 8;
    const ushort* bpl = Bplo + (size_t)(X * 192 + tg * 64 + l15) * KT + quad * 8;
    f32x4 acc[2][4];
    #pragma unroll
    for (int r = 0; r < 2; r++)
        #pragma unroll
        for (int c = 0; c < 4; c++) acc[r][c] = (f32x4){0.f, 0.f, 0.f, 0.f};
    #pragma unroll
    for (int k0 = 0; k0 < KT; k0 += 32) {
        bf16x8 ah0 = *reinterpret_cast<const bf16x8*>(aph + k0);
        bf16x8 al0 = *reinterpret_cast<const bf16x8*>(apl + k0);
        bf16x8 ah1 = *reinterpret_cast<const bf16x8*>(aph + (size_t)16 * KT + k0);
        bf16x8 al1 = *reinterpret_cast<const bf16x8*>(apl + (size_t)16 * KT + k0);
        #pragma unroll
        for (int c = 0; c < 4; c++) {
            bf16x8 bh = *reinterpret_cast<const bf16x8*>(bph + (size_t)c * 16 * KT + k0);
            bf16x8 bl = *reinterpret_cast<const bf16x8*>(bpl + (size_t)c * 16 * KT + k0);
            acc[0][c] = MFMA(al0, bh, acc[0][c], 0, 0, 0);
            acc[0][c] = MFMA(ah0, bl, acc[0][c], 0, 0, 0);
            acc[0][c] = MFMA(ah0, bh, acc[0][c], 0, 0, 0);
            acc[1][c] = MFMA(al1, bh, acc[1][c], 0, 0, 0);
            acc[1][c] = MFMA(ah1, bl, acc[1][c], 0, 0, 0);
            acc[1][c] = MFMA(ah1, bh, acc[1][c], 0, 0, 0);
        }
    }
    // epilogue 1: + bias -> LDS (gate-major cols within block)
    #pragma unroll
    for (int rr = 0; rr < 2; rr++) {
        #pragma unroll
        for (int c = 0; c < 4; c++) {
            #pragma unroll
            for (int r = 0; r < 4; r++) {
                int lrow = rh * 32 + rr * 16 + quad * 4 + r;
                int gc   = c * 16 + l15;
                gl[lrow * LDG + tg * 64 + gc] = acc[rr][c][r] + bs2[tg * 128 + X * 64 + gc];
            }
        }
    }
    __syncthreads();
    // epilogue 2: gated update for 64 atoms x 64 channels
    int a0 = blockIdx.y * 64;
    for (int t = threadIdx.x; t < 64 * 64; t += 384) {
        int al = t >> 6, gc = t & 63;
        int a = a0 + al;
        if (a >= M) continue;
        int g = X * 64 + gc;
        float avv = gl[al * LDG + gc];
        float asv = gl[al * LDG + 64 + gc];
        float ass = gl[al * LDG + 128 + gc];
        size_t b = (size_t)a * 384 + g;
        float dot = 0.f;
        #pragma unroll
        for (int d = 0; d < 3; d++) {
            size_t idx = b + (size_t)d * 128;
            float u  = uv[idx];
            float w  = vvf[idx];
            float vb = b2f(vhi[idx]) + b2f(vlo[idx]);
            dot = fmaf(u, w, dot);
            v[idx] = vb + u * avv;
        }
        size_t st = (size_t)a * FEAT + g;
        float ns = s[st] + dot * asv + ass;
        s[st] = ns;
        ushort h = f2b(ns); shi[st] = h; slo[st] = f2b(ns - b2f(h));
    }
}

// ---------------- edge gather-reduce: 2 atoms / 256-thr block ---------------
// atom = blockIdx.x*2 + (tid>>7); f = tid&127. Two independent 128-thread
// halves — no syncs. Math identical to k_edge4t. FIRST=1: v==0, skip gathers.
template<int FIRST>
__global__ __launch_bounds__(256) void k_edge6(
    const float* __restrict__ phi, const float* __restrict__ vin,
    const int* __restrict__ EJ, const float* __restrict__ EREC,
    const int* __restrict__ row,
    const float* __restrict__ Wd, const float* __restrict__ bd,
    float* __restrict__ s, ushort* __restrict__ vhi, ushort* __restrict__ vlo)
{
    int i = blockIdx.x * 2 + (threadIdx.x >> 7);
    int f = threadIdx.x & 127;
    if (i >= N_ATOMS) return;
    float wdr[3 * N_RBF];
    #pragma unroll
    for (int r = 0; r < N_RBF; r++) {
        wdr[r]           = Wd[r*384 + f];
        wdr[N_RBF + r]   = Wd[r*384 + 128 + f];
        wdr[2*N_RBF + r] = Wd[r*384 + 256 + f];
    }
    float bd0 = bd[f], bd1 = bd[128 + f], bd2 = bd[256 + f];
    float sacc = 0.f, va0 = 0.f, va1 = 0.f, va2 = 0.f;
    int beg = row[i], end = row[i + 1];

    auto body = [&](int idx){
        int j = EJ[idx];
        const float4* rq = reinterpret_cast<const float4*>(EREC + (size_t)idx * 24);
        float4 q0 = rq[0], q1 = rq[1], q2 = rq[2], q3 = rq[3], q4 = rq[4], q5 = rq[5];
        float g[20] = {q1.x,q1.y,q1.z,q1.w, q2.x,q2.y,q2.z,q2.w,
                       q3.x,q3.y,q3.z,q3.w, q4.x,q4.y,q4.z,q4.w,
                       q5.x,q5.y,q5.z,q5.w};
        float w0 = bd0 * q0.x, w1 = bd1 * q0.x, w2 = bd2 * q0.x;
        #pragma unroll
        for (int r = 0; r < N_RBF; r++) {
            w0 = fmaf(g[r], wdr[r],           w0);
            w1 = fmaf(g[r], wdr[N_RBF + r],   w1);
            w2 = fmaf(g[r], wdr[2*N_RBF + r], w2);
        }
        size_t pj = (size_t)j * 384;
        float inv0 = phi[pj + f]       * w0;
        float inv1 = phi[pj + 128 + f] * w1;
        float inv2 = phi[pj + 256 + f] * w2;
        sacc += inv1;
        if (FIRST) {
            va0 = fmaf(q0.y, inv2, va0);
            va1 = fmaf(q0.z, inv2, va1);
            va2 = fmaf(q0.w, inv2, va2);
        } else {
            size_t vj = (size_t)j * 384 + f;
            va0 = fmaf(inv0, vin[vj],       fmaf(q0.y, inv2, va0));
            va1 = fmaf(inv0, vin[vj + 128], fmaf(q0.z, inv2, va1));
            va2 = fmaf(inv0, vin[vj + 256], fmaf(q0.w, inv2, va2));
        }
    };

    int idx = beg;
    for (; idx + 1 < end; idx += 2) { body(idx); body(idx + 1); }
    if (idx < end) body(idx);

    s[(size_t)i * FEAT + f] += sacc;
    size_t vi = (size_t)i * 384 + f;
    float n0, n1, n2;
    if (FIRST) { n0 = va0; n1 = va1; n2 = va2; }
    else { n0 = vin[vi] + va0; n1 = vin[vi + 128] + va1; n2 = vin[vi + 256] + va2; }
    ushort h;
    h = f2b(n0); vhi[vi]       = h; vlo[vi]       = f2b(n0 - b2f(h));
    h = f2b(n1); vhi[vi + 128] = h; vlo[vi + 128] = f2b(n1 - b2f(h));
    h = f2b(n2); vhi[vi + 256] = h; vlo[vi + 256] = f2b(n2 - b2f(h));
}

// ---------------- host ----------------
struct Pair { ushort* hi; ushort* lo; };

static inline void gemm3(Pair A, Pair B, const float* bias,
                         int M, int K, int N, int Npad, int act,
                         float* Cf, Pair C, hipStream_t s){
    dim3 g(Npad / 64, (M + 127) / 128), b(256);
    switch (K) {
    case 64:  k_gemm3t<64> <<<g, b, 0, s>>>(A.hi, A.lo, B.hi, B.lo, bias, M, N, act, Cf, C.hi, C.lo); break;
    case 128: k_gemm3t<128><<<g, b, 0, s>>>(A.hi, A.lo, B.hi, B.lo, bias, M, N, act, Cf, C.hi, C.lo); break;
    case 256: k_gemm3t<256><<<g, b, 0, s>>>(A.hi, A.lo, B.hi, B.lo, bias, M, N, act, Cf, C.hi, C.lo); break;
    }
}

extern "C" void kernel_launch(void* const* d_in, const int* in_sizes, int n_in,
                              void* d_out, int out_size, void* d_ws, size_t ws_size,
                              hipStream_t stream) {
    float* ws = (float*)d_ws;
    int* flag = (int*)d_ws;
    const int* z    = (const int*)d_in[1];
    const int* nbrs = (const int*)d_in[2];

    k_detect<<<1, 64, 0, stream>>>((const unsigned int*)d_in[0], flag);

    P13 cp; {
        const int cidx[13] = {0,3,5,7,8,9,13,15,17,19,21,23,25};
        for (int i = 0; i < 13; i++) cp.p[i] = d_in[cidx[i]];
    }
    k_cvt_all<<<(100517 + 255)/256, 256, 0, stream>>>(cp, ws, flag);

    ushort* wb = (ushort*)(ws + H_WT);
    P11 wp; {
        const int widx[11] = {4,6,10,11,12,14,16,18,20,22,24};
        for (int i = 0; i < 11; i++) wp.p[i] = d_in[widx[i]];
    }
    k_wt_all<<<(WT_TOTAL + 255)/256, 256, 0, stream>>>(wp, wb, flag);

    // CSR build + CSR-ordered geometry records
    int* cnt = (int*)(ws + F_CNT); int* row = (int*)(ws + F_ROW);
    int* cur = (int*)(ws + F_CUR); int* eid = (int*)(ws + F_EID);
    int* EJ  = (int*)(ws + F_EJ);  float* EREC = ws + F_EREC;
    k_zero_i<<<(N_ATOMS+255)/256, 256, 0, stream>>>(cnt, N_ATOMS);
    k_hist<<<(N_EDGES+255)/256, 256, 0, stream>>>(nbrs, cnt);
    k_scan<<<1, 256, 0, stream>>>(cnt, row, cur);
    k_fill<<<(N_EDGES+255)/256, 256, 0, stream>>>(nbrs, cur, eid);
    k_geom_csr<<<(N_EDGES+255)/256, 256, 0, stream>>>(ws + F_XYZ, nbrs, eid, EJ, EREC);

    float* S   = ws + F_S;
    float* V   = ws + F_V;
    float* PHI = ws + F_PHI;       // phi f32, then uv f32
    float* VV  = ws + F_VV;
    Pair SHL { (ushort*)(ws + H_SHI),  (ushort*)(ws + H_SLO)  };
    Pair VHL { (ushort*)(ws + H_VHI),  (ushort*)(ws + H_VLO)  };
    Pair HA  { (ushort*)(ws + H_HAHI), (ushort*)(ws + H_HALO) };
    Pair HB  { (ushort*)(ws + H_HBHI), (ushort*)(ws + H_HBLO) };
    Pair AF  { (ushort*)(ws + H_AFHI), (ushort*)(ws + H_AFLO) };
    Pair CAT { (ushort*)(ws + F_SPL),  (ushort*)(ws + F_SPL) + (size_t)M20P*256 };
    Pair NOP { nullptr, nullptr };

    k_init_s<<<(N_ATOMS*FEAT+255)/256, 256, 0, stream>>>(ws + F_EMB, z, S, SHL.hi, SHL.lo);

    for (int l = 0; l < N_CONV; l++) {
        gemm3(SHL, Pair{wb + O_W1T + l*16384, wb + O_WTOT + O_W1T + l*16384},
              ws + F_B1 + l*128, N_ATOMS, 128, 128, 128, 1, nullptr, HA, stream);
        gemm3(HA, Pair{wb + O_W2T + l*49152, wb + O_WTOT + O_W2T + l*49152},
              ws + F_B2 + l*384, N_ATOMS, 128, 384, 384, 0, PHI, NOP, stream);
        // edge gather-reduce: 2 atoms per 256-thr block
        if (l == 0)
            k_edge6<1><<<N_ATOMS/2, 256, 0, stream>>>(PHI, V, EJ, EREC, row,
                ws + F_WD + (size_t)l*20*384, ws + F_BD + l*384, S, VHL.hi, VHL.lo);
        else
            k_edge6<0><<<N_ATOMS/2, 256, 0, stream>>>(PHI, V, EJ, EREC, row,
                ws + F_WD + (size_t)l*20*384, ws + F_BD + l*384, S, VHL.hi, VHL.lo);
        // uv + vv dual GEMM with fused vnorm/cat (atom-aligned 126-row blocks)
        {
            dim3 g(2, 477), b(256);
            k_dual_vn<<<g, b, 0, stream>>>(VHL.hi, VHL.lo,
                                           wb + O_UT + l*16384, wb + O_WTOT + O_UT + l*16384,
                                           wb + O_VT + l*16384, wb + O_WTOT + O_VT + l*16384,
                                           S, PHI, VV, CAT.hi, CAT.lo);
        }
        gemm3(CAT, Pair{wb + O_WS1T + l*32768, wb + O_WTOT + O_WS1T + l*32768},
              ws + F_BS1 + l*128, N_ATOMS, 256, 128, 128, 1, nullptr, HB, stream);
        // Ws2 GEMM + fused gated update (permuted weights)
        {
            dim3 g(2, (N_ATOMS + 63) / 64), b(384);
            k_ws2up<<<g, b, 0, stream>>>(HB.hi, HB.lo,
                                         wb + O_WS2T + l*49152, wb + O_WTOT + O_WS2T + l*49152,
                                         ws + F_BS2 + l*384,
                                         PHI, VV, VHL.hi, VHL.lo,
                                         S, V, SHL.hi, SHL.lo, N_ATOMS);
        }
    }

    // readout
    gemm3(SHL, Pair{wb + O_WR1T, wb + O_WTOT + O_WR1T}, ws + F_BR1,
          N_ATOMS, 128, 128, 128, 1, nullptr, HA, stream);
    gemm3(HA,  Pair{wb + O_WR2T, wb + O_WTOT + O_WR2T}, ws + F_BR2,
          N_ATOMS, 128,  64,  64, 0, nullptr, AF, stream);
    gemm3(AF,  Pair{wb + O_WF1T, wb + O_WTOT + O_WF1T}, ws + F_BF1,
          N_ATOMS,  64, 128, 128, 1, nullptr, HB, stream);
    gemm3(HB,  Pair{wb + O_WF2T, wb + O_WTOT + O_WF2T}, ws + F_BF2,
          N_ATOMS, 128, 128, 128, 1, nullptr, HA, stream);
    gemm3(HA,  Pair{wb + O_WF3T, wb + O_WTOT + O_WF3T}, ws + F_BF3,
          N_ATOMS, 128, N_OUT_, 64, 0, ws + F_OUT, NOP, stream);

    k_store_out<<<(N_ATOMS*N_OUT_+255)/256, 256, 0, stream>>>(ws + F_OUT, d_out, N_ATOMS*N_OUT_, flag);
}

// Round 13
// 1261.509 us; speedup vs baseline: 1.1425x; 1.1425x over previous
//
#include <hip/hip_runtime.h>
#include <hip/hip_bf16.h>
#include <math.h>

#define N_ATOMS 20000
#define N_EDGES 320000
#define FEAT 128
#define N_RBF 20
#define N_CONV 3
#define N_OUT_ 5
#define PI_F 3.14159265358979f
#define M20P 20032
#define M60PAD 60160   // v-pair rows padded past 60102 (dual_vn 126-row overlap reads)

typedef unsigned short ushort;
typedef __bf16 bf16x8 __attribute__((ext_vector_type(8)));
typedef float f32x4 __attribute__((ext_vector_type(4)));

__device__ __forceinline__ float b2f(ushort u){ return __uint_as_float(((unsigned)u) << 16); }
__device__ __forceinline__ ushort f2b(float x){
    unsigned u = __float_as_uint(x);
    return (ushort)((u + 0x7FFFu + ((u >> 16) & 1u)) >> 16);   // RNE
}
#define MFMA __builtin_amdgcn_mfma_f32_16x16x32_bf16

// ---------------- workspace layout (float slots) ----------------
constexpr size_t rnd64(size_t x){ return (x + 63) & ~size_t(63); }
constexpr size_t F_XYZ  = 64;                                  // flag at ws[0]
constexpr size_t F_EMB  = rnd64(F_XYZ + 60000);
constexpr size_t F_B1   = rnd64(F_EMB + 12800);
constexpr size_t F_B2   = rnd64(F_B1  + 3*128);
constexpr size_t F_WD   = rnd64(F_B2  + 3*384);
constexpr size_t F_BD   = rnd64(F_WD  + 3*20*384);
constexpr size_t F_BS1  = rnd64(F_BD  + 3*384);
constexpr size_t F_BS2  = rnd64(F_BS1 + 3*128);
constexpr size_t F_BR1  = rnd64(F_BS2 + 3*384);
constexpr size_t F_BR2  = rnd64(F_BR1 + 128);
constexpr size_t F_BF1  = rnd64(F_BR2 + 64);
constexpr size_t F_BF2  = rnd64(F_BF1 + 128);
constexpr size_t F_BF3  = rnd64(F_BF2 + 128);
constexpr size_t F_CNT  = rnd64(F_BF3 + 8);                    // int
constexpr size_t F_ROW  = rnd64(F_CNT  + N_ATOMS);             // int, +1
constexpr size_t F_CUR  = rnd64(F_ROW  + N_ATOMS + 1);         // int
constexpr size_t F_EID  = rnd64(F_CUR  + N_ATOMS);             // int
constexpr size_t F_EJ   = rnd64(F_EID  + N_EDGES);             // int, CSR-ordered j
constexpr size_t F_EREC = rnd64(F_EJ   + N_EDGES);             // 24 floats/edge, CSR order
constexpr size_t F_S    = rnd64(F_EREC + (size_t)N_EDGES*24);
constexpr size_t F_V    = rnd64(F_S    + (size_t)N_ATOMS*FEAT);
constexpr size_t F_PHI  = rnd64(F_V    + (size_t)60000*FEAT);     // phi f32, later uv f32
constexpr size_t F_VV   = rnd64(F_PHI  + (size_t)N_ATOMS*384);
constexpr size_t F_SPL  = rnd64(F_VV   + (size_t)60000*FEAT);     // CAT hi/lo lives here
constexpr size_t F_OUT  = rnd64(F_SPL  + (size_t)N_ATOMS*384);
// bf16 hi/lo pair buffers (slot counts = elems/2)
constexpr size_t H_SHI  = rnd64(F_OUT  + N_ATOMS*N_OUT_);
constexpr size_t H_SLO  = rnd64(H_SHI  + (size_t)M20P*128/2);
constexpr size_t H_VHI  = rnd64(H_SLO  + (size_t)M20P*128/2);
constexpr size_t H_VLO  = rnd64(H_VHI  + (size_t)M60PAD*128/2);
constexpr size_t H_HAHI = rnd64(H_VLO  + (size_t)M60PAD*128/2);
constexpr size_t H_HALO = rnd64(H_HAHI + (size_t)M20P*128/2);
constexpr size_t H_HBHI = rnd64(H_HALO + (size_t)M20P*128/2);
constexpr size_t H_HBLO = rnd64(H_HBHI + (size_t)M20P*128/2);
constexpr size_t H_AFHI = rnd64(H_HBLO + (size_t)M20P*128/2);
constexpr size_t H_AFLO = rnd64(H_AFHI + (size_t)M20P*64/2);
constexpr size_t H_WT   = rnd64(H_AFLO + (size_t)M20P*64/2);
// weight offsets (ushort elems within hi half; lo = +O_WTOT)
constexpr size_t O_W1T=0, O_W2T=49152, O_UT=196608, O_VT=245760, O_WS1T=294912,
                 O_WS2T=393216, O_WR1T=540672, O_WR2T=557056, O_WF1T=565248,
                 O_WF2T=573440, O_WF3T=589824, O_WTOT=598016;

// ---------------- dtype detection ----------------
__global__ void k_detect(const unsigned int* __restrict__ bits, int* flag){
    __shared__ int cnt;
    if (threadIdx.x == 0) cnt = 0;
    __syncthreads();
    unsigned int lo = bits[threadIdx.x] & 0xFFFFu;
    if (lo >= 0x3000u && lo <= 0x4100u) atomicAdd(&cnt, 1);
    __syncthreads();
    if (threadIdx.x == 0) *flag = (cnt >= 48) ? 1 : 0;
}

// ---------------- mega f32-convert (13 segments, 1 launch) ----------------
struct P13 { const void* p[13]; };
__global__ void k_cvt_all(P13 sp, float* __restrict__ ws, const int* __restrict__ flag){
    constexpr int   NSEG = 13;
    constexpr int    SZ[NSEG] = {60000,12800,384,1152,23040,1152,384,1152,128,64,128,128,5};
    constexpr size_t DO_[NSEG]= {F_XYZ,F_EMB,F_B1,F_B2,F_WD,F_BD,F_BS1,F_BS2,F_BR1,F_BR2,F_BF1,F_BF2,F_BF3};
    int t = blockIdx.x * blockDim.x + threadIdx.x;
    int bf = *flag;
    #pragma unroll
    for (int s = 0; s < NSEG; s++){
        if (t < SZ[s]){
            float v = bf ? b2f(((const ushort*)sp.p[s])[t]) : ((const float*)sp.p[s])[t];
            ws[DO_[s] + t] = v;
            return;
        }
        t -= SZ[s];
    }
}

// ---------------- mega weight transpose hi/lo (23 segments, 1 launch) -------
// PM=1 segments (Ws2): output-channel rows permuted gate-major:
// n -> (g/64)*192 + gate*64 + (g%64), g=n&127, gate=n>>7  (for k_ws2up)
struct P11 { const void* p[11]; };
__global__ void k_wt_all(P11 sp, ushort* __restrict__ wb, const int* __restrict__ flag){
    constexpr int NSEG = 23;
    constexpr int SRC[NSEG]  = {0,1,2,3,4,5, 0,1,2,3,4,5, 0,1,2,3,4,5, 6,7,8,9,10};
    constexpr int SOFF[NSEG] = {0,0,0,0,0,0, 16384,49152,16384,16384,32768,49152,
                                32768,98304,32768,32768,65536,98304, 0,0,0,0,0};
    constexpr size_t DOFF[NSEG]={O_W1T,O_W2T,O_UT,O_VT,O_WS1T,O_WS2T,
                                 O_W1T+16384,O_W2T+49152,O_UT+16384,O_VT+16384,O_WS1T+32768,O_WS2T+49152,
                                 O_W1T+32768,O_W2T+98304,O_UT+32768,O_VT+32768,O_WS1T+65536,O_WS2T+98304,
                                 O_WR1T,O_WR2T,O_WF1T,O_WF2T,O_WF3T};
    constexpr int KK[NSEG]   = {128,128,128,128,256,128, 128,128,128,128,256,128,
                                128,128,128,128,256,128, 128,128,64,128,128};
    constexpr int NN[NSEG]   = {128,384,128,128,128,384, 128,384,128,128,128,384,
                                128,384,128,128,128,384, 128,64,128,128,5};
    constexpr int NP[NSEG]   = {128,384,128,128,128,384, 128,384,128,128,128,384,
                                128,384,128,128,128,384, 128,64,128,128,64};
    constexpr int PM[NSEG]   = {0,0,0,0,0,1, 0,0,0,0,0,1, 0,0,0,0,0,1, 0,0,0,0,0};
    int t = blockIdx.x * blockDim.x + threadIdx.x;
    int bf = *flag;
    #pragma unroll
    for (int s = 0; s < NSEG; s++){
        int tot = NP[s] * KK[s];
        if (t < tot){
            int n = t / KK[s], k = t & (KK[s] - 1);
            ushort hi = 0, lo = 0;
            if (n < NN[s]){
                int si = SOFF[s] + k * NN[s] + n;
                float w = bf ? b2f(((const ushort*)sp.p[SRC[s]])[si])
                             : ((const float*)sp.p[SRC[s]])[si];
                hi = f2b(w); lo = f2b(w - b2f(hi));
            }
            int dr = n;
            if (PM[s]) { int g = n & 127, tg = n >> 7; dr = (g >> 6) * 192 + tg * 64 + (g & 63); }
            size_t di = DOFF[s] + (size_t)dr * KK[s] + k;
            wb[di] = hi;
            wb[O_WTOT + di] = lo;
            return;
        }
        t -= tot;
    }
}
constexpr int WT_TOTAL = 598016;

__global__ void k_store_out(const float* __restrict__ src, void* __restrict__ dst, int n,
                            const int* __restrict__ flag){
    int t = blockIdx.x * blockDim.x + threadIdx.x;
    if (t >= n) return;
    float v = src[t];
    if (*flag) ((ushort*)dst)[t] = f2b(v);
    else       ((float*)dst)[t] = v;
}

// ---------------- utility ----------------
__global__ void k_zero_i(int* p, int n){
    int t = blockIdx.x * blockDim.x + threadIdx.x;
    if (t < n) p[t] = 0;
}
__global__ void k_init_s(const float* __restrict__ embed, const int* __restrict__ z,
                         float* __restrict__ s, ushort* __restrict__ shi,
                         ushort* __restrict__ slo){
    int t = blockIdx.x * blockDim.x + threadIdx.x;
    if (t >= N_ATOMS * FEAT) return;
    int n = t >> 7, f = t & 127;
    float v = embed[z[n] * FEAT + f];
    s[t] = v;
    ushort h = f2b(v); shi[t] = h; slo[t] = f2b(v - b2f(h));
}

// ---------------- CSR build ----------------
__global__ void k_hist(const int* __restrict__ nbrs, int* __restrict__ cnt){
    int e = blockIdx.x * blockDim.x + threadIdx.x;
    if (e < N_EDGES) atomicAdd(&cnt[nbrs[2*e]], 1);
}
__global__ void k_scan(const int* __restrict__ cnt, int* __restrict__ row, int* __restrict__ cur){
    __shared__ int ls[256];
    int t = threadIdx.x, base = t * 80;
    int s = 0;
    for (int k = 0; k < 80; k++){ int i = base + k; if (i < N_ATOMS) s += cnt[i]; }
    ls[t] = s; __syncthreads();
    for (int off = 1; off < 256; off <<= 1){
        int v = (t >= off) ? ls[t - off] : 0;
        __syncthreads();
        ls[t] += v;
        __syncthreads();
    }
    int run = ls[t] - s;
    for (int k = 0; k < 80; k++){
        int i = base + k;
        if (i < N_ATOMS){ row[i] = run; cur[i] = run; run += cnt[i]; }
    }
    if (t == 255) row[N_ATOMS] = ls[255];
}
__global__ void k_fill(const int* __restrict__ nbrs, int* __restrict__ cur, int* __restrict__ eid){
    int e = blockIdx.x * blockDim.x + threadIdx.x;
    if (e >= N_EDGES) return;
    int p = atomicAdd(&cur[nbrs[2*e]], 1);
    eid[p] = e;
}

// ---------------- geometry in CSR order: EJ + packed 24-float record --------
__global__ void k_geom_csr(const float* __restrict__ xyz, const int* __restrict__ nbrs,
                           const int* __restrict__ eid,
                           int* __restrict__ EJ, float* __restrict__ EREC){
    int idx = blockIdx.x * blockDim.x + threadIdx.x;
    if (idx >= N_EDGES) return;
    int e = eid[idx];
    int i = nbrs[2*e], j = nbrs[2*e+1];
    float rx = xyz[3*j]   - xyz[3*i];
    float ry = xyz[3*j+1] - xyz[3*i+1];
    float rz = xyz[3*j+2] - xyz[3*i+2];
    float d  = sqrtf(rx*rx + ry*ry + rz*rz + 1e-12f);
    float inv = 1.0f / d;
    float b  = PI_F * d * 0.2f;
    float sb = sinf(b), cb = cosf(b);
    float fc = (d < 5.0f) ? 0.5f * (cb + 1.0f) : 0.0f;
    float scale = inv * fc, c2 = 2.0f * cb;
    EJ[idx] = j;
    float* rec = EREC + (size_t)idx * 24;
    rec[0] = fc; rec[1] = rx*inv; rec[2] = ry*inv; rec[3] = rz*inv;
    float sp = 0.f, sc = sb;
    #pragma unroll
    for (int r = 0; r < N_RBF; r++){
        rec[4 + r] = sc * scale;
        float sn = c2 * sc - sp;
        sp = sc; sc = sn;
    }
}

// ---------------- split-bf16 MFMA GEMM, fat wave tile 32x64 ----------------
template<int KT>
__global__ __launch_bounds__(256) void k_gemm3t(
    const ushort* __restrict__ Ahi, const ushort* __restrict__ Alo,
    const ushort* __restrict__ Bthi, const ushort* __restrict__ Btlo,
    const float* __restrict__ bias, int M, int N, int act,
    float* __restrict__ Cf, ushort* __restrict__ Chi, ushort* __restrict__ Clo)
{
    int wave = threadIdx.x >> 6, lane = threadIdx.x & 63;
    int l15 = lane & 15, quad = lane >> 4;
    int m0 = blockIdx.y * 128 + wave * 32;
    int n0 = blockIdx.x * 64;
    const ushort* aph = Ahi  + (size_t)(m0 + l15) * KT + quad * 8;
    const ushort* apl = Alo  + (size_t)(m0 + l15) * KT + quad * 8;
    const ushort* bph = Bthi + (size_t)(n0 + l15) * KT + quad * 8;
    const ushort* bpl = Btlo + (size_t)(n0 + l15) * KT + quad * 8;
    f32x4 acc[2][4];
    #pragma unroll
    for (int r = 0; r < 2; r++)
        #pragma unroll
        for (int c = 0; c < 4; c++) acc[r][c] = (f32x4){0.f, 0.f, 0.f, 0.f};
    #pragma unroll
    for (int k0 = 0; k0 < KT; k0 += 32) {
        bf16x8 ah0 = *reinterpret_cast<const bf16x8*>(aph + k0);
        bf16x8 al0 = *reinterpret_cast<const bf16x8*>(apl + k0);
        bf16x8 ah1 = *reinterpret_cast<const bf16x8*>(aph + (size_t)16 * KT + k0);
        bf16x8 al1 = *reinterpret_cast<const bf16x8*>(apl + (size_t)16 * KT + k0);
        #pragma unroll
        for (int c = 0; c < 4; c++) {
            bf16x8 bh = *reinterpret_cast<const bf16x8*>(bph + (size_t)c * 16 * KT + k0);
            bf16x8 bl = *reinterpret_cast<const bf16x8*>(bpl + (size_t)c * 16 * KT + k0);
            acc[0][c] = MFMA(al0, bh, acc[0][c], 0, 0, 0);
            acc[0][c] = MFMA(ah0, bl, acc[0][c], 0, 0, 0);
            acc[0][c] = MFMA(ah0, bh, acc[0][c], 0, 0, 0);
            acc[1][c] = MFMA(al1, bh, acc[1][c], 0, 0, 0);
            acc[1][c] = MFMA(ah1, bl, acc[1][c], 0, 0, 0);
            acc[1][c] = MFMA(ah1, bh, acc[1][c], 0, 0, 0);
        }
    }
    #pragma unroll
    for (int rr = 0; rr < 2; rr++) {
        int row_base = m0 + rr * 16 + quad * 4;
        #pragma unroll
        for (int c = 0; c < 4; c++) {
            int col = n0 + c * 16 + l15;
            #pragma unroll
            for (int r = 0; r < 4; r++) {
                int row = row_base + r;
                if (row < M && col < N) {
                    float v = acc[rr][c][r];
                    if (bias) v += bias[col];
                    if (act)  v = v / (1.f + expf(-v));
                    size_t idx = (size_t)row * N + col;
                    if (Cf)  Cf[idx] = v;
                    if (Chi) { ushort h = f2b(v); Chi[idx] = h; Clo[idx] = f2b(v - b2f(h)); }
                }
            }
        }
    }
}

// ---------------- dual GEMM (uv,vv) + fused vnorm/cat, atom-aligned 126-row --
__global__ __launch_bounds__(256) void k_dual_vn(
    const ushort* __restrict__ Ahi, const ushort* __restrict__ Alo,
    const ushort* __restrict__ B1hi, const ushort* __restrict__ B1lo,
    const ushort* __restrict__ B2hi, const ushort* __restrict__ B2lo,
    const float* __restrict__ s,
    float* __restrict__ C1, float* __restrict__ C2,
    ushort* __restrict__ chi, ushort* __restrict__ clo)
{
    constexpr int KT = 128, N = 128, MROWS = 60000, LDV = 68;
    __shared__ float vvs[128 * LDV];   // 34.8 KB
    int wave = threadIdx.x >> 6, lane = threadIdx.x & 63;
    int l15 = lane & 15, quad = lane >> 4;
    int m0 = blockIdx.y * 126 + wave * 32;
    int n0 = blockIdx.x * 64;
    const ushort* aph = Ahi  + (size_t)(m0 + l15) * KT + quad * 8;
    const ushort* apl = Alo  + (size_t)(m0 + l15) * KT + quad * 8;
    const ushort* b1h = B1hi + (size_t)(n0 + l15) * KT + quad * 8;
    const ushort* b1l = B1lo + (size_t)(n0 + l15) * KT + quad * 8;
    const ushort* b2h = B2hi + (size_t)(n0 + l15) * KT + quad * 8;
    const ushort* b2l = B2lo + (size_t)(n0 + l15) * KT + quad * 8;
    f32x4 acc1[2][4], acc2[2][4];
    #pragma unroll
    for (int r = 0; r < 2; r++)
        #pragma unroll
        for (int c = 0; c < 4; c++) {
            acc1[r][c] = (f32x4){0.f,0.f,0.f,0.f};
            acc2[r][c] = (f32x4){0.f,0.f,0.f,0.f};
        }
    #pragma unroll
    for (int k0 = 0; k0 < KT; k0 += 32) {
        bf16x8 ah0 = *reinterpret_cast<const bf16x8*>(aph + k0);
        bf16x8 al0 = *reinterpret_cast<const bf16x8*>(apl + k0);
        bf16x8 ah1 = *reinterpret_cast<const bf16x8*>(aph + (size_t)16 * KT + k0);
        bf16x8 al1 = *reinterpret_cast<const bf16x8*>(apl + (size_t)16 * KT + k0);
        #pragma unroll
        for (int c = 0; c < 4; c++) {
            bf16x8 bh = *reinterpret_cast<const bf16x8*>(b1h + (size_t)c * 16 * KT + k0);
            bf16x8 bl = *reinterpret_cast<const bf16x8*>(b1l + (size_t)c * 16 * KT + k0);
            acc1[0][c] = MFMA(al0, bh, acc1[0][c], 0, 0, 0);
            acc1[0][c] = MFMA(ah0, bl, acc1[0][c], 0, 0, 0);
            acc1[0][c] = MFMA(ah0, bh, acc1[0][c], 0, 0, 0);
            acc1[1][c] = MFMA(al1, bh, acc1[1][c], 0, 0, 0);
            acc1[1][c] = MFMA(ah1, bl, acc1[1][c], 0, 0, 0);
            acc1[1][c] = MFMA(ah1, bh, acc1[1][c], 0, 0, 0);
        }
        #pragma unroll
        for (int c = 0; c < 4; c++) {
            bf16x8 bh = *reinterpret_cast<const bf16x8*>(b2h + (size_t)c * 16 * KT + k0);
            bf16x8 bl = *reinterpret_cast<const bf16x8*>(b2l + (size_t)c * 16 * KT + k0);
            acc2[0][c] = MFMA(al0, bh, acc2[0][c], 0, 0, 0);
            acc2[0][c] = MFMA(ah0, bl, acc2[0][c], 0, 0, 0);
            acc2[0][c] = MFMA(ah0, bh, acc2[0][c], 0, 0, 0);
            acc2[1][c] = MFMA(al1, bh, acc2[1][c], 0, 0, 0);
            acc2[1][c] = MFMA(ah1, bl, acc2[1][c], 0, 0, 0);
            acc2[1][c] = MFMA(ah1, bh, acc2[1][c], 0, 0, 0);
        }
    }
    #pragma unroll
    for (int rr = 0; rr < 2; rr++) {
        #pragma unroll
        for (int c = 0; c < 4; c++) {
            int col = n0 + c * 16 + l15;
            #pragma unroll
            for (int r = 0; r < 4; r++) {
                int lrow = wave * 32 + rr * 16 + quad * 4 + r;
                int row  = m0 + rr * 16 + quad * 4 + r;
                float vv = acc2[rr][c][r];
                vvs[lrow * LDV + c * 16 + l15] = vv;
                if (row < MROWS) {
                    size_t idx = (size_t)row * N + col;
                    C1[idx] = acc1[rr][c][r];
                    C2[idx] = vv;
                }
            }
        }
    }
    __syncthreads();
    // vnorm + cat for 42 atoms x 64 cols (LDS rows a_loc*3+d)
    int a0 = blockIdx.y * 42;
    for (int t = threadIdx.x; t < 42 * 64; t += 256) {
        int a_loc = t >> 6, c = t & 63;
        int a = a0 + a_loc;
        if (a >= N_ATOMS) continue;
        float v0 = vvs[(a_loc * 3 + 0) * LDV + c];
        float v1 = vvs[(a_loc * 3 + 1) * LDV + c];
        float v2 = vvs[(a_loc * 3 + 2) * LDV + c];
        float nr = sqrtf(v0 * v0 + v1 * v1 + v2 * v2 + 1e-12f);
        int g = n0 + c;
        float sv = s[(size_t)a * FEAT + g];
        size_t c0 = (size_t)a * 256 + g;
        ushort h;
        h = f2b(sv); chi[c0]       = h; clo[c0]       = f2b(sv - b2f(h));
        h = f2b(nr); chi[c0 + 128] = h; clo[c0 + 128] = f2b(nr - b2f(h));
    }
}

// ---------------- Ws2 GEMM (permuted cols) + fused gated update -------------
__global__ __launch_bounds__(384) void k_ws2up(
    const ushort* __restrict__ Ahi, const ushort* __restrict__ Alo,
    const ushort* __restrict__ Bphi, const ushort* __restrict__ Bplo,
    const float* __restrict__ bs2,
    const float* __restrict__ uv, const float* __restrict__ vvf,
    const ushort* __restrict__ vhi, const ushort* __restrict__ vlo,
    float* __restrict__ s, float* __restrict__ v,
    ushort* __restrict__ shi, ushort* __restrict__ slo, int M)
{
    constexpr int KT = 128, LDG = 200;          // 192 cols + 8 pad
    __shared__ float gl[64 * LDG];               // 50 KB -> 3 blocks/CU
    int wave = threadIdx.x >> 6, lane = threadIdx.x & 63;
    int l15 = lane & 15, quad = lane >> 4;
    int tg = wave >> 1, rh = wave & 1;           // gate, row-half
    int m0 = blockIdx.y * 64 + rh * 32;
    int X  = blockIdx.x;                         // g-half
    const ushort* aph = Ahi  + (size_t)(m0 + l15) * KT + quad * 8;
    const ushort* apl = Alo  + (size_t)(m0 + l15) * KT + quad * 8;
    const ushort* bph = Bphi + (size_t)(X * 192 + tg * 64 + l15) * KT + quad * 8;
    const ushort* bpl = Bplo + (size_t)(X * 192 + tg * 64 + l15) * KT + quad * 8;
    f32x4 acc[2][4];
    #pragma unroll
    for (int r = 0; r < 2; r++)
        #pragma unroll
        for (int c = 0; c < 4; c++) acc[r][c] = (f32x4){0.f, 0.f, 0.f, 0.f};
    #pragma unroll
    for (int k0 = 0; k0 < KT; k0 += 32) {
        bf16x8 ah0 = *reinterpret_cast<const bf16x8*>(aph + k0);
        bf16x8 al0 = *reinterpret_cast<const bf16x8*>(apl + k0);
        bf16x8 ah1 = *reinterpret_cast<const bf16x8*>(aph + (size_t)16 * KT + k0);
        bf16x8 al1 = *reinterpret_cast<const bf16x8*>(apl + (size_t)16 * KT + k0);
        #pragma unroll
        for (int c = 0; c < 4; c++) {
            bf16x8 bh = *reinterpret_cast<const bf16x8*>(bph + (size_t)c * 16 * KT + k0);
            bf16x8 bl = *reinterpret_cast<const bf16x8*>(bpl + (size_t)c * 16 * KT + k0);
            acc[0][c] = MFMA(al0, bh, acc[0][c], 0, 0, 0);
            acc[0][c] = MFMA(ah0, bl, acc[0][c], 0, 0, 0);
            acc[0][c] = MFMA(ah0, bh, acc[0][c], 0, 0, 0);
            acc[1][c] = MFMA(al1, bh, acc[1][c], 0, 0, 0);
            acc[1][c] = MFMA(ah1, bl, acc[1][c], 0, 0, 0);
            acc[1][c] = MFMA(ah1, bh, acc[1][c], 0, 0, 0);
        }
    }
    // epilogue 1: + bias -> LDS (gate-major cols within block)
    #pragma unroll
    for (int rr = 0; rr < 2; rr++) {
        #pragma unroll
        for (int c = 0; c < 4; c++) {
            #pragma unroll
            for (int r = 0; r < 4; r++) {
                int lrow = rh * 32 + rr * 16 + quad * 4 + r;
                int gc   = c * 16 + l15;
                gl[lrow * LDG + tg * 64 + gc] = acc[rr][c][r] + bs2[tg * 128 + X * 64 + gc];
            }
        }
    }
    __syncthreads();
    // epilogue 2: gated update for 64 atoms x 64 channels
    int a0 = blockIdx.y * 64;
    for (int t = threadIdx.x; t < 64 * 64; t += 384) {
        int al = t >> 6, gc = t & 63;
        int a = a0 + al;
        if (a >= M) continue;
        int g = X * 64 + gc;
        float avv = gl[al * LDG + gc];
        float asv = gl[al * LDG + 64 + gc];
        float ass = gl[al * LDG + 128 + gc];
        size_t b = (size_t)a * 384 + g;
        float dot = 0.f;
        #pragma unroll
        for (int d = 0; d < 3; d++) {
            size_t idx = b + (size_t)d * 128;
            float u  = uv[idx];
            float w  = vvf[idx];
            float vb = b2f(vhi[idx]) + b2f(vlo[idx]);
            dot = fmaf(u, w, dot);
            v[idx] = vb + u * avv;
        }
        size_t st = (size_t)a * FEAT + g;
        float ns = s[st] + dot * asv + ass;
        s[st] = ns;
        ushort h = f2b(ns); shi[st] = h; slo[st] = f2b(ns - b2f(h));
    }
}

// ---------------- edge gather-reduce: CSR records, 2x unroll ----------------
// FIRST=1: layer 0, v==0 -> skip vin gathers (exact: fmaf(x,0,y)==y)
template<int FIRST>
__global__ __launch_bounds__(128) void k_edge4t(
    const float* __restrict__ phi, const float* __restrict__ vin,
    const int* __restrict__ EJ, const float* __restrict__ EREC,
    const int* __restrict__ row,
    const float* __restrict__ Wd, const float* __restrict__ bd,
    float* __restrict__ s, ushort* __restrict__ vhi, ushort* __restrict__ vlo)
{
    int i = blockIdx.x, f = threadIdx.x;
    float wdr[3 * N_RBF];
    #pragma unroll
    for (int r = 0; r < N_RBF; r++) {
        wdr[r]           = Wd[r*384 + f];
        wdr[N_RBF + r]   = Wd[r*384 + 128 + f];
        wdr[2*N_RBF + r] = Wd[r*384 + 256 + f];
    }
    float bd0 = bd[f], bd1 = bd[128 + f], bd2 = bd[256 + f];
    float sacc = 0.f, va0 = 0.f, va1 = 0.f, va2 = 0.f;
    int beg = row[i], end = row[i + 1];

    auto body = [&](int idx){
        int j = EJ[idx];
        const float4* rq = reinterpret_cast<const float4*>(EREC + (size_t)idx * 24);
        float4 q0 = rq[0], q1 = rq[1], q2 = rq[2], q3 = rq[3], q4 = rq[4], q5 = rq[5];
        float g[20] = {q1.x,q1.y,q1.z,q1.w, q2.x,q2.y,q2.z,q2.w,
                       q3.x,q3.y,q3.z,q3.w, q4.x,q4.y,q4.z,q4.w,
                       q5.x,q5.y,q5.z,q5.w};
        float w0 = bd0 * q0.x, w1 = bd1 * q0.x, w2 = bd2 * q0.x;
        #pragma unroll
        for (int r = 0; r < N_RBF; r++) {
            w0 = fmaf(g[r], wdr[r],           w0);
            w1 = fmaf(g[r], wdr[N_RBF + r],   w1);
            w2 = fmaf(g[r], wdr[2*N_RBF + r], w2);
        }
        size_t pj = (size_t)j * 384;
        float inv0 = phi[pj + f]       * w0;
        float inv1 = phi[pj + 128 + f] * w1;
        float inv2 = phi[pj + 256 + f] * w2;
        sacc += inv1;
        if (FIRST) {
            va0 = fmaf(q0.y, inv2, va0);
            va1 = fmaf(q0.z, inv2, va1);
            va2 = fmaf(q0.w, inv2, va2);
        } else {
            size_t vj = (size_t)j * 384 + f;
            va0 = fmaf(inv0, vin[vj],       fmaf(q0.y, inv2, va0));
            va1 = fmaf(inv0, vin[vj + 128], fmaf(q0.z, inv2, va1));
            va2 = fmaf(inv0, vin[vj + 256], fmaf(q0.w, inv2, va2));
        }
    };

    int idx = beg;
    for (; idx + 1 < end; idx += 2) { body(idx); body(idx + 1); }
    if (idx < end) body(idx);

    s[(size_t)i * FEAT + f] += sacc;
    size_t vi = (size_t)i * 384 + f;
    float n0, n1, n2;
    if (FIRST) { n0 = va0; n1 = va1; n2 = va2; }
    else { n0 = vin[vi] + va0; n1 = vin[vi + 128] + va1; n2 = vin[vi + 256] + va2; }
    ushort h;
    h = f2b(n0); vhi[vi]       = h; vlo[vi]       = f2b(n0 - b2f(h));
    h = f2b(n1); vhi[vi + 128] = h; vlo[vi + 128] = f2b(n1 - b2f(h));
    h = f2b(n2); vhi[vi + 256] = h; vlo[vi + 256] = f2b(n2 - b2f(h));
}

// ---------------- host ----------------
struct Pair { ushort* hi; ushort* lo; };

static inline void gemm3(Pair A, Pair B, const float* bias,
                         int M, int K, int N, int Npad, int act,
                         float* Cf, Pair C, hipStream_t s){
    dim3 g(Npad / 64, (M + 127) / 128), b(256);
    switch (K) {
    case 64:  k_gemm3t<64> <<<g, b, 0, s>>>(A.hi, A.lo, B.hi, B.lo, bias, M, N, act, Cf, C.hi, C.lo); break;
    case 128: k_gemm3t<128><<<g, b, 0, s>>>(A.hi, A.lo, B.hi, B.lo, bias, M, N, act, Cf, C.hi, C.lo); break;
    case 256: k_gemm3t<256><<<g, b, 0, s>>>(A.hi, A.lo, B.hi, B.lo, bias, M, N, act, Cf, C.hi, C.lo); break;
    }
}

extern "C" void kernel_launch(void* const* d_in, const int* in_sizes, int n_in,
                              void* d_out, int out_size, void* d_ws, size_t ws_size,
                              hipStream_t stream) {
    float* ws = (float*)d_ws;
    int* flag = (int*)d_ws;
    const int* z    = (const int*)d_in[1];
    const int* nbrs = (const int*)d_in[2];

    k_detect<<<1, 64, 0, stream>>>((const unsigned int*)d_in[0], flag);

    P13 cp; {
        const int cidx[13] = {0,3,5,7,8,9,13,15,17,19,21,23,25};
        for (int i = 0; i < 13; i++) cp.p[i] = d_in[cidx[i]];
    }
    k_cvt_all<<<(100517 + 255)/256, 256, 0, stream>>>(cp, ws, flag);

    ushort* wb = (ushort*)(ws + H_WT);
    P11 wp; {
        const int widx[11] = {4,6,10,11,12,14,16,18,20,22,24};
        for (int i = 0; i < 11; i++) wp.p[i] = d_in[widx[i]];
    }
    k_wt_all<<<(WT_TOTAL + 255)/256, 256, 0, stream>>>(wp, wb, flag);

    // CSR build + CSR-ordered geometry records
    int* cnt = (int*)(ws + F_CNT); int* row = (int*)(ws + F_ROW);
    int* cur = (int*)(ws + F_CUR); int* eid = (int*)(ws + F_EID);
    int* EJ  = (int*)(ws + F_EJ);  float* EREC = ws + F_EREC;
    k_zero_i<<<(N_ATOMS+255)/256, 256, 0, stream>>>(cnt, N_ATOMS);
    k_hist<<<(N_EDGES+255)/256, 256, 0, stream>>>(nbrs, cnt);
    k_scan<<<1, 256, 0, stream>>>(cnt, row, cur);
    k_fill<<<(N_EDGES+255)/256, 256, 0, stream>>>(nbrs, cur, eid);
    k_geom_csr<<<(N_EDGES+255)/256, 256, 0, stream>>>(ws + F_XYZ, nbrs, eid, EJ, EREC);

    float* S   = ws + F_S;
    float* V   = ws + F_V;
    float* PHI = ws + F_PHI;       // phi f32, then uv f32
    float* VV  = ws + F_VV;
    Pair SHL { (ushort*)(ws + H_SHI),  (ushort*)(ws + H_SLO)  };
    Pair VHL { (ushort*)(ws + H_VHI),  (ushort*)(ws + H_VLO)  };
    Pair HA  { (ushort*)(ws + H_HAHI), (ushort*)(ws + H_HALO) };
    Pair HB  { (ushort*)(ws + H_HBHI), (ushort*)(ws + H_HBLO) };
    Pair AF  { (ushort*)(ws + H_AFHI), (ushort*)(ws + H_AFLO) };
    Pair CAT { (ushort*)(ws + F_SPL),  (ushort*)(ws + F_SPL) + (size_t)M20P*256 };
    Pair NOP { nullptr, nullptr };

    k_init_s<<<(N_ATOMS*FEAT+255)/256, 256, 0, stream>>>(ws + F_EMB, z, S, SHL.hi, SHL.lo);
    // no V zero-init needed: layer-0 edge (FIRST=1) never reads V, and
    // layer-0 k_ws2up writes all of V before layer-1 edge reads it.

    for (int l = 0; l < N_CONV; l++) {
        gemm3(SHL, Pair{wb + O_W1T + l*16384, wb + O_WTOT + O_W1T + l*16384},
              ws + F_B1 + l*128, N_ATOMS, 128, 128, 128, 1, nullptr, HA, stream);
        gemm3(HA, Pair{wb + O_W2T + l*49152, wb + O_WTOT + O_W2T + l*49152},
              ws + F_B2 + l*384, N_ATOMS, 128, 384, 384, 0, PHI, NOP, stream);
        // edge gather-reduce (20000 blocks, 128 thr, dynamic scheduling — proven)
        if (l == 0)
            k_edge4t<1><<<N_ATOMS, 128, 0, stream>>>(PHI, V, EJ, EREC, row,
                ws + F_WD + (size_t)l*20*384, ws + F_BD + l*384, S, VHL.hi, VHL.lo);
        else
            k_edge4t<0><<<N_ATOMS, 128, 0, stream>>>(PHI, V, EJ, EREC, row,
                ws + F_WD + (size_t)l*20*384, ws + F_BD + l*384, S, VHL.hi, VHL.lo);
        // uv + vv dual GEMM with fused vnorm/cat (atom-aligned 126-row blocks)
        {
            dim3 g(2, 477), b(256);
            k_dual_vn<<<g, b, 0, stream>>>(VHL.hi, VHL.lo,
                                           wb + O_UT + l*16384, wb + O_WTOT + O_UT + l*16384,
                                           wb + O_VT + l*16384, wb + O_WTOT + O_VT + l*16384,
                                           S, PHI, VV, CAT.hi, CAT.lo);
        }
        gemm3(CAT, Pair{wb + O_WS1T + l*32768, wb + O_WTOT + O_WS1T + l*32768},
              ws + F_BS1 + l*128, N_ATOMS, 256, 128, 128, 1, nullptr, HB, stream);
        // Ws2 GEMM + fused gated update (permuted weights)
        {
            dim3 g(2, (N_ATOMS + 63) / 64), b(384);
            k_ws2up<<<g, b, 0, stream>>>(HB.hi, HB.lo,
                                         wb + O_WS2T + l*49152, wb + O_WTOT + O_WS2T + l*49152,
                                         ws + F_BS2 + l*384,
                                         PHI, VV, VHL.hi, VHL.lo,
                                         S, V, SHL.hi, SHL.lo, N_ATOMS);
        }
    }

    // readout
    gemm3(SHL, Pair{wb + O_WR1T, wb + O_WTOT + O_WR1T}, ws + F_BR1,
          N_ATOMS, 128, 128, 128, 1, nullptr, HA, stream);
    gemm3(HA,  Pair{wb + O_WR2T, wb + O_WTOT + O_WR2T}, ws + F_BR2,
          N_ATOMS, 128,  64,  64, 0, nullptr, AF, stream);
    gemm3(AF,  Pair{wb + O_WF1T, wb + O_WTOT + O_WF1T}, ws + F_BF1,
          N_ATOMS,  64, 128, 128, 1, nullptr, HB, stream);
    gemm3(HB,  Pair{wb + O_WF2T, wb + O_WTOT + O_WF2T}, ws + F_BF2,
          N_ATOMS, 128, 128, 128, 1, nullptr, HA, stream);
    gemm3(HA,  Pair{wb + O_WF3T, wb + O_WTOT + O_WF3T}, ws + F_BF3,
          N_ATOMS, 128, N_OUT_, 64, 0, ws + F_OUT, NOP, stream);

    k_store_out<<<(N_ATOMS*N_OUT_+255)/256, 256, 0, stream>>>(ws + F_OUT, d_out, N_ATOMS*N_OUT_, flag);
}